// Round 9
// baseline (348.012 us; speedup 1.0000x reference)
//
#include <hip/hip_runtime.h>

typedef unsigned short u16;
typedef unsigned int u32;
typedef __attribute__((ext_vector_type(4))) float f32x4;
typedef __attribute__((ext_vector_type(8))) short short8;
typedef __attribute__((ext_vector_type(4))) short short4v;

#define BB   2
#define SQL  2048
#define SKVL 4096
#define DM   1024
#define NH   16
#define DK   64
#define L2E  1.44269504f

#if __has_builtin(__builtin_amdgcn_exp2f)
#define EXP2(x) __builtin_amdgcn_exp2f(x)
#else
#define EXP2(x) exp2f(x)
#endif

#define MFMA32(a, b, c) __builtin_amdgcn_mfma_f32_16x16x32_bf16(a, b, c, 0, 0, 0)

__device__ __forceinline__ u16 f2bf(float f) {
  union { float f; unsigned u; } v; v.f = f;
  unsigned r = v.u + 0x7fff + ((v.u >> 16) & 1);   // RNE
  return (u16)(r >> 16);
}

// pack4 via v_perm_b32: hi16(a)|hi16(b)<<16 after round-half-up
__device__ __forceinline__ short4v pack4(float p0, float p1, float p2, float p3) {
  union { float f; u32 u; } a, b, c, d;
  a.f = p0; b.f = p1; c.f = p2; d.f = p3;
  union { uint2 v; short4v s; } r;
  r.v.x = __builtin_amdgcn_perm(b.u + 0x8000u, a.u + 0x8000u, 0x07060302);
  r.v.y = __builtin_amdgcn_perm(d.u + 0x8000u, c.u + 0x8000u, 0x07060302);
  return r.s;
}

// async global->LDS, 16B per lane; lds base wave-uniform, lane i -> base + i*16.
__device__ __forceinline__ void gload16(const void* g, void* lds) {
  __builtin_amdgcn_global_load_lds(
      (const __attribute__((address_space(1))) unsigned int*)g,
      (__attribute__((address_space(3))) unsigned int*)lds, 16, 0, 0);
}

// ---------------- fused preprocessing: rmsnorm | fp32->bf16 cvt | 4x weight transpose ----------------
__global__ void pre_kernel(const float* __restrict__ hidden, const float* __restrict__ lnw,
                           const float* __restrict__ kvs,
                           const float* __restrict__ Wq, const float* __restrict__ Wk,
                           const float* __restrict__ Wv, const float* __restrict__ Wo,
                           u16* __restrict__ normed, u16* __restrict__ kvb,
                           u16* __restrict__ Wqt, u16* __restrict__ Wkt,
                           u16* __restrict__ Wvt, u16* __restrict__ Wot) {
  __shared__ float red[4];
  __shared__ float tile[32][33];
  int bid = blockIdx.x, t = threadIdx.x;
  if (bid < 4096) {
    int row = bid;
    float4 v = ((const float4*)(hidden + (size_t)row * DM))[t];
    float ss = v.x * v.x + v.y * v.y + v.z * v.z + v.w * v.w;
#pragma unroll
    for (int m = 32; m >= 1; m >>= 1) ss += __shfl_xor(ss, m, 64);
    int lane = t & 63, wv = t >> 6;
    if (lane == 0) red[wv] = ss;
    __syncthreads();
    float total = red[0] + red[1] + red[2] + red[3];
    float scale = rsqrtf(total * (1.0f / DM) + 1e-6f);
    float4 g = ((const float4*)lnw)[t];
    ushort4 o;
    o.x = f2bf(v.x * scale * g.x);
    o.y = f2bf(v.y * scale * g.y);
    o.z = f2bf(v.z * scale * g.z);
    o.w = f2bf(v.w * scale * g.w);
    ((ushort4*)(normed + (size_t)row * DM))[t] = o;
  } else if (bid < 12288) {
    int i = (bid - 4096) * 256 + t;
    float4 v = ((const float4*)kvs)[i];
    ushort4 o;
    o.x = f2bf(v.x); o.y = f2bf(v.y); o.z = f2bf(v.z); o.w = f2bf(v.w);
    ((ushort4*)kvb)[i] = o;
  } else {
    int g = bid - 12288;
    int z = g >> 10;
    const float* W = (z == 0) ? Wq : (z == 1) ? Wk : (z == 2) ? Wv : Wo;
    u16* Wt = (z == 0) ? Wqt : (z == 1) ? Wkt : (z == 2) ? Wvt : Wot;
    int xx = g & 31, yy = (g >> 5) & 31;
    int tx = t & 31, ty = t >> 5;
    int k0 = yy * 32, n0 = xx * 32;
#pragma unroll
    for (int i = 0; i < 4; i++)
      tile[ty + i * 8][tx] = W[(size_t)(k0 + ty + i * 8) * DM + n0 + tx];
    __syncthreads();
#pragma unroll
    for (int i = 0; i < 4; i++)
      Wt[(size_t)(n0 + ty + i * 8) * DM + k0 + tx] = f2bf(tile[tx][ty + i * 8]);
  }
}

// ---------------- merged projections, 2-phase double-buffered loop (round-8, verified) ----------------
__global__ __launch_bounds__(512, 2) void proj_kernel(
    const u16* __restrict__ normed, const u16* __restrict__ kvb,
    const u16* __restrict__ Wqt, const u16* __restrict__ Wkt,
    const u16* __restrict__ Wvt,
    u16* __restrict__ Qb, u16* __restrict__ Kbf, u16* __restrict__ Vtb) {
  const int K = 1024;
  __shared__ __align__(16) u16 Al[2][256 * 32];   // 32KB (Q uses first half rows)
  __shared__ __align__(16) u16 B1[2][128 * 32];   // 16KB
  __shared__ __align__(16) u16 B2[2][128 * 32];   // 16KB (KV only)
  int tid = threadIdx.x, lane = tid & 63, w = tid >> 6;   // 8 waves
  int l15 = lane & 15, quad = lane >> 4;
  int wy = w >> 1, wx = w & 1;
  int bid = blockIdx.x;

  if (bid < 256) {
    // ---- KV block: tile 256(kv) x 128(d), wave grid 4x2 of 64x64 ----
    int tm = (bid >> 3) * 256, tn = (bid & 7) * 128;
    f32x4 ak[4][4] = {}, av[4][4] = {};

    auto stage = [&](int k0, int buf) {
#pragma unroll
      for (int r = 0; r < 2; r++) {
        int mg = w * 2 + r;
        gload16(kvb + (size_t)(tm + mg * 16 + l15) * K + k0 + quad * 8, &Al[buf][mg * 512]);
      }
      gload16(Wkt + (size_t)(tn + w * 16 + l15) * K + k0 + quad * 8, &B1[buf][w * 512]);
      gload16(Wvt + (size_t)(tn + w * 16 + l15) * K + k0 + quad * 8, &B2[buf][w * 512]);
    };

    stage(0, 0);
    __syncthreads();
    for (int k0 = 0; k0 < K; k0 += 32) {
      int cur = (k0 >> 5) & 1;
      if (k0 + 32 < K) stage(k0 + 32, cur ^ 1);   // prefetch flies during compute below
      short8 af[4], bk[4], bv[4];
#pragma unroll
      for (int i = 0; i < 4; i++) {
        af[i] = *(const short8*)&Al[cur][((wy * 4 + i) * 64 + lane) * 8];
        bk[i] = *(const short8*)&B1[cur][((wx * 4 + i) * 64 + lane) * 8];
        bv[i] = *(const short8*)&B2[cur][((wx * 4 + i) * 64 + lane) * 8];
      }
#pragma unroll
      for (int mt = 0; mt < 4; mt++)
#pragma unroll
        for (int nt = 0; nt < 4; nt++) {
          ak[mt][nt] = MFMA32(af[mt], bk[nt], ak[mt][nt]);
          av[mt][nt] = MFMA32(af[mt], bv[nt], av[mt][nt]);
        }
      __syncthreads();                     // readers done + prefetch landed
    }
#pragma unroll
    for (int mt = 0; mt < 4; mt++) {
      int m0 = tm + wy * 64 + mt * 16 + quad * 4;        // kv row (0..8191)
      int bB = m0 >> 12, skv0 = m0 & 4095;
      int t32 = skv0 >> 5, p0 = skv0 & 31;               // p0..p0+3 stay within tile32
#pragma unroll
      for (int nt = 0; nt < 4; nt++) {
        int n = tn + wx * 64 + nt * 16 + l15;            // d col (0..1023)
        int h = n >> 6, d0 = n & 63;
        size_t vbase = ((size_t)((bB * NH + h) * 128 + t32)) * 2048
                     + (size_t)(d0 >> 4) * 512 + (size_t)(d0 & 15) * 8;
#pragma unroll
        for (int r = 0; r < 4; r++) {
          Kbf[(size_t)(m0 + r) * 1024 + n] = f2bf(ak[mt][nt][r]);
          int p = p0 + r;
          int s = ((p >> 2) & 3) * 8 + ((p >> 4) & 1) * 4 + (p & 3);
          Vtb[vbase + (s >> 3) * 128 + (s & 7)] = f2bf(av[mt][nt][r]);
        }
      }
    }
  } else {
    // ---- Q block: tile 128 x 128, wave grid 4x2 of 32x64; 256 blocks (32m x 8n) ----
    int qid = bid - 256;
    int tm = (qid >> 3) * 128, tn = (qid & 7) * 128;
    f32x4 acc[2][4] = {};

    auto stage = [&](int k0, int buf) {
      gload16(normed + (size_t)(tm + w * 16 + l15) * K + k0 + quad * 8, &Al[buf][w * 512]);
      gload16(Wqt + (size_t)(tn + w * 16 + l15) * K + k0 + quad * 8, &B1[buf][w * 512]);
    };

    stage(0, 0);
    __syncthreads();
    for (int k0 = 0; k0 < K; k0 += 32) {
      int cur = (k0 >> 5) & 1;
      if (k0 + 32 < K) stage(k0 + 32, cur ^ 1);
      short8 af[2], bfr[4];
#pragma unroll
      for (int i = 0; i < 2; i++)
        af[i] = *(const short8*)&Al[cur][((wy * 2 + i) * 64 + lane) * 8];
#pragma unroll
      for (int i = 0; i < 4; i++)
        bfr[i] = *(const short8*)&B1[cur][((wx * 4 + i) * 64 + lane) * 8];
#pragma unroll
      for (int mt = 0; mt < 2; mt++)
#pragma unroll
        for (int nt = 0; nt < 4; nt++)
          acc[mt][nt] = MFMA32(af[mt], bfr[nt], acc[mt][nt]);
      __syncthreads();
    }
#pragma unroll
    for (int mt = 0; mt < 2; mt++) {
      int m0 = tm + wy * 32 + mt * 16 + quad * 4;
#pragma unroll
      for (int nt = 0; nt < 4; nt++) {
        int n = tn + wx * 64 + nt * 16 + l15;
#pragma unroll
        for (int r = 0; r < 4; r++)
          Qb[(size_t)(m0 + r) * 1024 + n] = f2bf(acc[mt][nt][r] * L2E);
      }
    }
  }
}

// ---------------- flash attention v2: 8 waves (4 kv-grps x 2 q-halves), 64 q-rows/wave,
// KVBLK=32 per iter, dbuf K+V (64KB), 16 waves/CU. 4-way sequential LDS merge. ----------------
__global__ __launch_bounds__(512, 2) void flash_kernel(
    const u16* __restrict__ Qp, const u16* __restrict__ Kp, const u16* __restrict__ Vtb,
    const float* __restrict__ mask, u16* __restrict__ ctx) {
  __shared__ __align__(16) char smem[65536];
  u16* Kbuf = (u16*)smem;                 // [grp4][buf2][2048 u16] = 32KB
  u16* Vbuf = (u16*)(smem + 32768);       // [grp4][buf2][2048 u16] = 32KB
  float* Ox = (float*)smem;               // merge reuse: [128][64] = 32KB
  float* Ll = (float*)(smem + 32768);     // merge reuse: [128]

  int tid = threadIdx.x, lane = tid & 63, w = tid >> 6;   // 8 waves
  int l15 = lane & 15, quad = lane >> 4;
  int grp = w >> 1, wg = w & 1;           // grp 0..3 = kv quarter; wg = q half

  // XCD-aware remap: XCD x owns heads [4x,4x+4) with all 16 qb tiles (4MB K/V fits L2).
  int lid = blockIdx.y * 16 + blockIdx.x;        // 0..511
  int xcd = lid & 7, slot = lid >> 3;            // 64 slots per xcd
  int bh = xcd * 4 + (slot >> 4);
  int qb = slot & 15;
  int b = bh >> 4, h = bh & 15;
  int q0 = qb * 128 + wg * 64;

  short8 qf[4][2];
#pragma unroll
  for (int mt = 0; mt < 4; mt++)
#pragma unroll
    for (int kf = 0; kf < 2; kf++)
      qf[mt][kf] = *(const short8*)(Qp + (size_t)(b * SQL + q0 + mt * 16 + l15) * DM +
                                    h * DK + kf * 32 + quad * 8);

  f32x4 of[4][4] = {};
  f32x4 la[4] = {};
  const short8 ones8 = {0x3F80, 0x3F80, 0x3F80, 0x3F80, 0x3F80, 0x3F80, 0x3F80, 0x3F80};

  const size_t vblob = (size_t)(b * NH + h) * 262144;   // 512KB/head in u16
  const float* mrow = mask + (size_t)b * SKVL;

  // per tile32: K = 4 chunks of 1KB (kt,kf), V = 4 chunks of 1KB; wave stages 2 of each
  auto stage = [&](int it, int buf) {
    int t32 = grp * 32 + it;              // this grp's kv quarter
    u16* Kd = Kbuf + (grp * 2 + buf) * 2048;
    u16* Vd = Vbuf + (grp * 2 + buf) * 2048;
#pragma unroll
    for (int r = 0; r < 2; r++) {
      int c = wg * 2 + r;
      int kt = c >> 1, kf = c & 1;
      gload16(Kp + (size_t)(b * SKVL + t32 * 32 + kt * 16 + l15) * DM + h * DK + kf * 32 + quad * 8,
              &Kd[c * 512]);
      gload16(Vtb + vblob + (size_t)t32 * 2048 + c * 512 + lane * 8, &Vd[c * 512]);
    }
  };

  // mask (C-init values): mlc[kt] covers kv = t32*32 + kt*16 + quad*4 .. +3
  f32x4 mlc[2], mln[2];
#pragma unroll
  for (int kt = 0; kt < 2; kt++)
    mlc[kt] = *(const f32x4*)(mrow + grp * 1024 + kt * 16 + quad * 4) * L2E;
  stage(0, 0);

  union PU { short8 v8; short4v h2[2]; };

  for (int it = 0; it < 32; ++it) {
    __syncthreads();                      // tile it landed (loads issued last iter)
    if (it + 1 < 32) {
      stage(it + 1, (it + 1) & 1);
      int kvn = (grp * 32 + it + 1) * 32;
#pragma unroll
      for (int kt = 0; kt < 2; kt++)
        mln[kt] = *(const f32x4*)(mrow + kvn + kt * 16 + quad * 4) * L2E;
    }
    const u16* Kg = Kbuf + (grp * 2 + (it & 1)) * 2048;
    const u16* Vg = Vbuf + (grp * 2 + (it & 1)) * 2048;

    __builtin_amdgcn_s_setprio(1);
    PU paf[4];
#pragma unroll
    for (int kt = 0; kt < 2; kt++) {
      short8 k0 = *(const short8*)&Kg[((kt * 2 + 0) * 64 + lane) * 8];
      short8 k1 = *(const short8*)&Kg[((kt * 2 + 1) * 64 + lane) * 8];
#pragma unroll
      for (int mt = 0; mt < 4; mt++) {
        f32x4 st = mlc[kt];               // mask*log2e as accumulator init
        st = MFMA32(k0, qf[mt][0], st);
        st = MFMA32(k1, qf[mt][1], st);
        paf[mt].h2[kt] = pack4(EXP2(st[0]), EXP2(st[1]), EXP2(st[2]), EXP2(st[3]));
      }
    }
#pragma unroll
    for (int mt = 0; mt < 4; mt++)        // l rowsum on full-rate mfma32
      la[mt] = MFMA32(paf[mt].v8, ones8, la[mt]);
#pragma unroll
    for (int nt = 0; nt < 4; nt++) {      // PV: lane-contiguous 1KB read per nt
      short8 vv = *(const short8*)&Vg[(nt * 64 + lane) * 8];
#pragma unroll
      for (int mt = 0; mt < 4; mt++)
        of[mt][nt] = MFMA32(paf[mt].v8, vv, of[mt][nt]);
    }
    __builtin_amdgcn_s_setprio(0);
#pragma unroll
    for (int kt = 0; kt < 2; kt++) mlc[kt] = mln[kt];
  }

  // 4-way sequential merge across kv-grps. Rows ql = wg*64 + mt*16 + quad*4 + r.
  __syncthreads();
  if (grp == 3) {
#pragma unroll
    for (int mt = 0; mt < 4; mt++) {
#pragma unroll
      for (int nt = 0; nt < 4; nt++)
#pragma unroll
        for (int r = 0; r < 4; r++)
          Ox[(wg * 64 + mt * 16 + quad * 4 + r) * 64 + nt * 16 + l15] = of[mt][nt][r];
      if (l15 == 0)
#pragma unroll
        for (int r = 0; r < 4; r++) Ll[wg * 64 + mt * 16 + quad * 4 + r] = la[mt][r];
    }
  }
  __syncthreads();
  if (grp == 2) {
#pragma unroll
    for (int mt = 0; mt < 4; mt++) {
#pragma unroll
      for (int nt = 0; nt < 4; nt++)
#pragma unroll
        for (int r = 0; r < 4; r++)
          Ox[(wg * 64 + mt * 16 + quad * 4 + r) * 64 + nt * 16 + l15] += of[mt][nt][r];
      if (l15 == 0)
#pragma unroll
        for (int r = 0; r < 4; r++) Ll[wg * 64 + mt * 16 + quad * 4 + r] += la[mt][r];
    }
  }
  __syncthreads();
  if (grp == 1) {
#pragma unroll
    for (int mt = 0; mt < 4; mt++) {
#pragma unroll
      for (int nt = 0; nt < 4; nt++)
#pragma unroll
        for (int r = 0; r < 4; r++)
          Ox[(wg * 64 + mt * 16 + quad * 4 + r) * 64 + nt * 16 + l15] += of[mt][nt][r];
      if (l15 == 0)
#pragma unroll
        for (int r = 0; r < 4; r++) Ll[wg * 64 + mt * 16 + quad * 4 + r] += la[mt][r];
    }
  }
  __syncthreads();
  if (grp == 0) {
#pragma unroll
    for (int mt = 0; mt < 4; mt++)
#pragma unroll
      for (int r = 0; r < 4; r++) {
        int ql = wg * 64 + mt * 16 + quad * 4 + r;
        float inv = 1.0f / (la[mt][r] + Ll[ql]);
        int q = qb * 128 + ql;
#pragma unroll
        for (int nt = 0; nt < 4; nt++) {
          float ov = of[mt][nt][r] + Ox[ql * 64 + nt * 16 + l15];
          ctx[(size_t)(b * SQL + q) * DM + h * DK + nt * 16 + l15] = f2bf(ov * inv);
        }
      }
  }
}

// ---------------- O projection + residual (round-0 measured-best loop, 128x128) ----------------
__global__ void ogemm_kernel(const u16* __restrict__ A, const u16* __restrict__ Bt,
                             float* __restrict__ C, const float* __restrict__ resid) {
  const int K = 1024;
  __shared__ __align__(16) u16 Al[128 * 32];
  __shared__ __align__(16) u16 Bl[128 * 32];
  int tid = threadIdx.x, lane = tid & 63, w = tid >> 6;
  int l15 = lane & 15, quad = lane >> 4;
  int wy = w >> 1, wx = w & 1;
  int tm = blockIdx.x * 128, tn = blockIdx.y * 128;
  f32x4 acc[4][4] = {};

  for (int k0 = 0; k0 < K; k0 += 32) {
    __syncthreads();
#pragma unroll
    for (int r = 0; r < 2; r++) {
      int mg = w * 2 + r;
      gload16(A + (size_t)(tm + mg * 16 + l15) * K + k0 + quad * 8, &Al[mg * 512]);
      gload16(Bt + (size_t)(tn + mg * 16 + l15) * K + k0 + quad * 8, &Bl[mg * 512]);
    }
    __syncthreads();
    short8 af[4], bfr[4];
#pragma unroll
    for (int i = 0; i < 4; i++) {
      af[i] = *(const short8*)&Al[((wy * 4 + i) * 64 + lane) * 8];
      bfr[i] = *(const short8*)&Bl[((wx * 4 + i) * 64 + lane) * 8];
    }
#pragma unroll
    for (int mt = 0; mt < 4; mt++)
#pragma unroll
      for (int nt = 0; nt < 4; nt++)
        acc[mt][nt] = MFMA32(af[mt], bfr[nt], acc[mt][nt]);
  }

#pragma unroll
  for (int mt = 0; mt < 4; mt++) {
    int m0 = tm + wy * 64 + mt * 16 + quad * 4;
#pragma unroll
    for (int nt = 0; nt < 4; nt++) {
      int n = tn + wx * 64 + nt * 16 + l15;
#pragma unroll
      for (int r = 0; r < 4; r++) {
        size_t idx = (size_t)(m0 + r) * 1024 + n;
        C[idx] = resid[idx] + acc[mt][nt][r];
      }
    }
  }
}

extern "C" void kernel_launch(void* const* d_in, const int* in_sizes, int n_in,
                              void* d_out, int out_size, void* d_ws, size_t ws_size,
                              hipStream_t stream) {
  const float* hidden = (const float*)d_in[0];
  const float* kvs    = (const float*)d_in[1];
  const float* mask   = (const float*)d_in[2];
  const float* lnw    = (const float*)d_in[3];
  const float* Wq     = (const float*)d_in[4];
  const float* Wk     = (const float*)d_in[5];
  const float* Wv     = (const float*)d_in[6];
  const float* Wo     = (const float*)d_in[7];
  char* ws = (char*)d_ws;

  u16* normed = (u16*)(ws + 0);           // 8 MB
  u16* kvb    = (u16*)(ws + 8388608);     // 16 MB
  u16* Wqt    = (u16*)(ws + 25165824);    // 2 MB
  u16* Wkt    = (u16*)(ws + 27262976);    // 2 MB
  u16* Wvt    = (u16*)(ws + 29360128);    // 2 MB
  u16* Wot    = (u16*)(ws + 31457280);    // 2 MB
  u16* Qb     = (u16*)(ws + 33554432);    // 8 MB (pre-scaled by log2e)
  u16* Kbf    = (u16*)(ws + 41943040);    // 16 MB
  u16* Vtb    = (u16*)(ws + 58720256);    // 16 MB (chunked mfma32 blob layout)
  u16* ctxb   = (u16*)(ws + 75497472);    // 8 MB

  pre_kernel<<<16384, 256, 0, stream>>>(hidden, lnw, kvs, Wq, Wk, Wv, Wo,
                                        normed, kvb, Wqt, Wkt, Wvt, Wot);
  proj_kernel<<<512, 512, 0, stream>>>(normed, kvb, Wqt, Wkt, Wvt, Qb, Kbf, Vtb);
  flash_kernel<<<dim3(SQL / 128, BB * NH), 512, 0, stream>>>(Qb, Kbf, Vtb, mask, ctxb);
  ogemm_kernel<<<dim3(32, 8), 256, 0, stream>>>(ctxb, Wot, (float*)d_out, hidden);
}

// Round 11
// 303.340 us; speedup vs baseline: 1.1473x; 1.1473x over previous
//
#include <hip/hip_runtime.h>

typedef unsigned short u16;
typedef unsigned int u32;
typedef __attribute__((ext_vector_type(4))) float f32x4;
typedef __attribute__((ext_vector_type(8))) short short8;
typedef __attribute__((ext_vector_type(4))) short short4v;

#define BB   2
#define SQL  2048
#define SKVL 4096
#define DM   1024
#define NH   16
#define DK   64
#define L2E  1.44269504f

#if __has_builtin(__builtin_amdgcn_exp2f)
#define EXP2(x) __builtin_amdgcn_exp2f(x)
#else
#define EXP2(x) exp2f(x)
#endif

#define MFMA32(a, b, c) __builtin_amdgcn_mfma_f32_16x16x32_bf16(a, b, c, 0, 0, 0)

__device__ __forceinline__ u16 f2bf(float f) {
  union { float f; unsigned u; } v; v.f = f;
  unsigned r = v.u + 0x7fff + ((v.u >> 16) & 1);   // RNE
  return (u16)(r >> 16);
}

// pack4 via v_perm_b32: hi16(a)|hi16(b)<<16 after round-half-up
__device__ __forceinline__ short4v pack4(float p0, float p1, float p2, float p3) {
  union { float f; u32 u; } a, b, c, d;
  a.f = p0; b.f = p1; c.f = p2; d.f = p3;
  union { uint2 v; short4v s; } r;
  r.v.x = __builtin_amdgcn_perm(b.u + 0x8000u, a.u + 0x8000u, 0x07060302);
  r.v.y = __builtin_amdgcn_perm(d.u + 0x8000u, c.u + 0x8000u, 0x07060302);
  return r.s;
}

// async global->LDS, 16B per lane; lds base wave-uniform, lane i -> base + i*16.
__device__ __forceinline__ void gload16(const void* g, void* lds) {
  __builtin_amdgcn_global_load_lds(
      (const __attribute__((address_space(1))) unsigned int*)g,
      (__attribute__((address_space(3))) unsigned int*)lds, 16, 0, 0);
}

// ---------------- fused preprocessing: rmsnorm | fp32->bf16 cvt | 4x weight transpose ----------------
__global__ void pre_kernel(const float* __restrict__ hidden, const float* __restrict__ lnw,
                           const float* __restrict__ kvs,
                           const float* __restrict__ Wq, const float* __restrict__ Wk,
                           const float* __restrict__ Wv, const float* __restrict__ Wo,
                           u16* __restrict__ normed, u16* __restrict__ kvb,
                           u16* __restrict__ Wqt, u16* __restrict__ Wkt,
                           u16* __restrict__ Wvt, u16* __restrict__ Wot) {
  __shared__ float red[4];
  __shared__ float tile[32][33];
  int bid = blockIdx.x, t = threadIdx.x;
  if (bid < 4096) {
    int row = bid;
    float4 v = ((const float4*)(hidden + (size_t)row * DM))[t];
    float ss = v.x * v.x + v.y * v.y + v.z * v.z + v.w * v.w;
#pragma unroll
    for (int m = 32; m >= 1; m >>= 1) ss += __shfl_xor(ss, m, 64);
    int lane = t & 63, wv = t >> 6;
    if (lane == 0) red[wv] = ss;
    __syncthreads();
    float total = red[0] + red[1] + red[2] + red[3];
    float scale = rsqrtf(total * (1.0f / DM) + 1e-6f);
    float4 g = ((const float4*)lnw)[t];
    ushort4 o;
    o.x = f2bf(v.x * scale * g.x);
    o.y = f2bf(v.y * scale * g.y);
    o.z = f2bf(v.z * scale * g.z);
    o.w = f2bf(v.w * scale * g.w);
    ((ushort4*)(normed + (size_t)row * DM))[t] = o;
  } else if (bid < 12288) {
    int i = (bid - 4096) * 256 + t;
    float4 v = ((const float4*)kvs)[i];
    ushort4 o;
    o.x = f2bf(v.x); o.y = f2bf(v.y); o.z = f2bf(v.z); o.w = f2bf(v.w);
    ((ushort4*)kvb)[i] = o;
  } else {
    int g = bid - 12288;
    int z = g >> 10;
    const float* W = (z == 0) ? Wq : (z == 1) ? Wk : (z == 2) ? Wv : Wo;
    u16* Wt = (z == 0) ? Wqt : (z == 1) ? Wkt : (z == 2) ? Wvt : Wot;
    int xx = g & 31, yy = (g >> 5) & 31;
    int tx = t & 31, ty = t >> 5;
    int k0 = yy * 32, n0 = xx * 32;
#pragma unroll
    for (int i = 0; i < 4; i++)
      tile[ty + i * 8][tx] = W[(size_t)(k0 + ty + i * 8) * DM + n0 + tx];
    __syncthreads();
#pragma unroll
    for (int i = 0; i < 4; i++)
      Wt[(size_t)(n0 + ty + i * 8) * DM + k0 + tx] = f2bf(tile[tx][ty + i * 8]);
  }
}

// ---------------- merged projections, 2-phase double-buffered loop.
// XCD mapping (HW: xcd = original bid % 8): bid = n*32 + m  ->  bid%8 = m%8, so each
// XCD owns 4 A-panels (kvb/normed, L2-resident) and re-reads the small weight set
// (4MB) with high L2 reuse. Old mapping streamed 24MB of A per XCD. ----------------
__global__ __launch_bounds__(512, 2) void proj_kernel(
    const u16* __restrict__ normed, const u16* __restrict__ kvb,
    const u16* __restrict__ Wqt, const u16* __restrict__ Wkt,
    const u16* __restrict__ Wvt,
    u16* __restrict__ Qb, u16* __restrict__ Kbf, u16* __restrict__ Vtb) {
  const int K = 1024;
  __shared__ __align__(16) u16 Al[2][256 * 32];   // 32KB (Q uses first half rows)
  __shared__ __align__(16) u16 B1[2][128 * 32];   // 16KB
  __shared__ __align__(16) u16 B2[2][128 * 32];   // 16KB (KV only)
  int tid = threadIdx.x, lane = tid & 63, w = tid >> 6;   // 8 waves
  int l15 = lane & 15, quad = lane >> 4;
  int wy = w >> 1, wx = w & 1;
  int bid = blockIdx.x;

  if (bid < 256) {
    // ---- KV block: tile 256(kv) x 128(d), wave grid 4x2 of 64x64 ----
    int tm = (bid & 31) * 256, tn = (bid >> 5) * 128;   // bid%8 = m%8 -> kvb panel L2-local
    f32x4 ak[4][4] = {}, av[4][4] = {};

    auto stage = [&](int k0, int buf) {
#pragma unroll
      for (int r = 0; r < 2; r++) {
        int mg = w * 2 + r;
        gload16(kvb + (size_t)(tm + mg * 16 + l15) * K + k0 + quad * 8, &Al[buf][mg * 512]);
      }
      gload16(Wkt + (size_t)(tn + w * 16 + l15) * K + k0 + quad * 8, &B1[buf][w * 512]);
      gload16(Wvt + (size_t)(tn + w * 16 + l15) * K + k0 + quad * 8, &B2[buf][w * 512]);
    };

    stage(0, 0);
    __syncthreads();
    for (int k0 = 0; k0 < K; k0 += 32) {
      int cur = (k0 >> 5) & 1;
      if (k0 + 32 < K) stage(k0 + 32, cur ^ 1);   // prefetch flies during compute below
      short8 af[4], bk[4], bv[4];
#pragma unroll
      for (int i = 0; i < 4; i++) {
        af[i] = *(const short8*)&Al[cur][((wy * 4 + i) * 64 + lane) * 8];
        bk[i] = *(const short8*)&B1[cur][((wx * 4 + i) * 64 + lane) * 8];
        bv[i] = *(const short8*)&B2[cur][((wx * 4 + i) * 64 + lane) * 8];
      }
#pragma unroll
      for (int mt = 0; mt < 4; mt++)
#pragma unroll
        for (int nt = 0; nt < 4; nt++) {
          ak[mt][nt] = MFMA32(af[mt], bk[nt], ak[mt][nt]);
          av[mt][nt] = MFMA32(af[mt], bv[nt], av[mt][nt]);
        }
      __syncthreads();                     // readers done + prefetch landed
    }
#pragma unroll
    for (int mt = 0; mt < 4; mt++) {
      int m0 = tm + wy * 64 + mt * 16 + quad * 4;        // kv row (0..8191)
      int bB = m0 >> 12, skv0 = m0 & 4095;
      int t32 = skv0 >> 5, p0 = skv0 & 31;               // p0..p0+3 stay within tile32
#pragma unroll
      for (int nt = 0; nt < 4; nt++) {
        int n = tn + wx * 64 + nt * 16 + l15;            // d col (0..1023)
        int h = n >> 6, d0 = n & 63;
        size_t vbase = ((size_t)((bB * NH + h) * 128 + t32)) * 2048
                     + (size_t)(d0 >> 4) * 512 + (size_t)(d0 & 15) * 8;
#pragma unroll
        for (int r = 0; r < 4; r++) {
          Kbf[(size_t)(m0 + r) * 1024 + n] = f2bf(ak[mt][nt][r]);
          int p = p0 + r;
          int s = ((p >> 2) & 3) * 8 + ((p >> 4) & 1) * 4 + (p & 3);
          Vtb[vbase + (s >> 3) * 128 + (s & 7)] = f2bf(av[mt][nt][r]);
        }
      }
    }
  } else {
    // ---- Q block: tile 128 x 128, wave grid 4x2 of 32x64; 256 blocks (32m x 8n) ----
    int qid = bid - 256;
    int tm = (qid & 31) * 128, tn = (qid >> 5) * 128;   // same m-local mapping
    f32x4 acc[2][4] = {};

    auto stage = [&](int k0, int buf) {
      gload16(normed + (size_t)(tm + w * 16 + l15) * K + k0 + quad * 8, &Al[buf][w * 512]);
      gload16(Wqt + (size_t)(tn + w * 16 + l15) * K + k0 + quad * 8, &B1[buf][w * 512]);
    };

    stage(0, 0);
    __syncthreads();
    for (int k0 = 0; k0 < K; k0 += 32) {
      int cur = (k0 >> 5) & 1;
      if (k0 + 32 < K) stage(k0 + 32, cur ^ 1);
      short8 af[2], bfr[4];
#pragma unroll
      for (int i = 0; i < 2; i++)
        af[i] = *(const short8*)&Al[cur][((wy * 2 + i) * 64 + lane) * 8];
#pragma unroll
      for (int i = 0; i < 4; i++)
        bfr[i] = *(const short8*)&B1[cur][((wx * 4 + i) * 64 + lane) * 8];
#pragma unroll
      for (int mt = 0; mt < 2; mt++)
#pragma unroll
        for (int nt = 0; nt < 4; nt++)
          acc[mt][nt] = MFMA32(af[mt], bfr[nt], acc[mt][nt]);
      __syncthreads();
    }
#pragma unroll
    for (int mt = 0; mt < 2; mt++) {
      int m0 = tm + wy * 32 + mt * 16 + quad * 4;
#pragma unroll
      for (int nt = 0; nt < 4; nt++) {
        int n = tn + wx * 64 + nt * 16 + l15;
#pragma unroll
        for (int r = 0; r < 4; r++)
          Qb[(size_t)(m0 + r) * 1024 + n] = f2bf(acc[mt][nt][r] * L2E);
      }
    }
  }
}

// ---------------- flash attention: 4 waves x 64 q-rows, kv-split + merge (measured-best 101us),
// conflict-free chunked V reads + XCD-aware block remap + setprio ----------------
__global__ __launch_bounds__(256, 2) void flash_kernel(
    const u16* __restrict__ Qp, const u16* __restrict__ Kp, const u16* __restrict__ Vtb,
    const float* __restrict__ mask, u16* __restrict__ ctx) {
  __shared__ __align__(16) char smem[65536];
  u16* Kbuf = (u16*)smem;                 // [buf2][grp2][4096]
  u16* Vbuf = (u16*)(smem + 32768);       // [buf2][grp2][4096]
  float* Ox = (float*)smem;               // merge reuse: [128][64]
  float* Ll = (float*)(smem + 32768);     // merge reuse: [128]

  int tid = threadIdx.x, lane = tid & 63, w = tid >> 6;
  int l15 = lane & 15, quad = lane >> 4;
  int grp = w >> 1, wg = w & 1;

  // XCD-aware remap: HW round-robins linear block id over 8 XCDs (id % 8).
  // Give XCD x the 4 heads [4x,4x+4) with all 16 qb tiles -> 4MB K/V set fits its L2.
  int lid = blockIdx.y * 16 + blockIdx.x;        // 0..511
  int xcd = lid & 7, slot = lid >> 3;            // 64 slots per xcd
  int bh = xcd * 4 + (slot >> 4);
  int qb = slot & 15;
  int b = bh >> 4, h = bh & 15;
  int q0 = qb * 128 + wg * 64;

  short8 qf[4][2];
#pragma unroll
  for (int mt = 0; mt < 4; mt++)
#pragma unroll
    for (int kf = 0; kf < 2; kf++)
      qf[mt][kf] = *(const short8*)(Qp + (size_t)(b * SQL + q0 + mt * 16 + l15) * DM +
                                    h * DK + kf * 32 + quad * 8);

  f32x4 of[4][4] = {};
  f32x4 la[4] = {};
  const short8 ones8 = {0x3F80, 0x3F80, 0x3F80, 0x3F80, 0x3F80, 0x3F80, 0x3F80, 0x3F80};

  const size_t vblob = (size_t)(b * NH + h) * 262144;   // 512KB/head in u16
  const float* mrow = mask + (size_t)b * SKVL;

  auto stage = [&](int tileIdx, int buf) {
    int kv0 = tileIdx * 64;
    u16* Kd = Kbuf + (buf * 2 + grp) * 4096;
    u16* Vd = Vbuf + (buf * 2 + grp) * 4096;
#pragma unroll
    for (int r = 0; r < 4; r++) {
      int u = wg * 4 + r;
      int kt = u >> 1, kf = u & 1;
      gload16(Kp + (size_t)(b * SKVL + kv0 + kt * 16 + l15) * DM + h * DK + kf * 32 + quad * 8,
              &Kd[u * 512]);
      // V blob is tile-linear: tile64 = 2 contiguous tile32 of 2048 u16 each
      gload16(Vtb + vblob + (size_t)tileIdx * 4096 + u * 512 + lane * 8, &Vd[u * 512]);
    }
  };

  // mask prefetch (C-init values): ml[kt] covers kv = tile*64 + kt*16 + quad*4 .. +3
  f32x4 mlc[4], mln[4];
  {
    int kv0 = grp * 64;
#pragma unroll
    for (int kt = 0; kt < 4; kt++)
      mlc[kt] = *(const f32x4*)(mrow + kv0 + kt * 16 + quad * 4) * L2E;
  }
  stage(grp, 0);

  union PU { short8 v8; short4v h2[2]; };

  for (int it = 0; it < 32; ++it) {
    __syncthreads();                      // tile it landed (loads issued last iter)
    if (it + 1 < 32) {
      stage((it + 1) * 2 + grp, (it + 1) & 1);
      int kvn = ((it + 1) * 2 + grp) * 64;
#pragma unroll
      for (int kt = 0; kt < 4; kt++)
        mln[kt] = *(const f32x4*)(mrow + kvn + kt * 16 + quad * 4) * L2E;
    }
    const u16* Kg = Kbuf + ((it & 1) * 2 + grp) * 4096;
    const u16* Vg = Vbuf + ((it & 1) * 2 + grp) * 4096;

    // T5: favor this wave's compute chain while other-block waves stage/wait.
    __builtin_amdgcn_s_setprio(1);
#pragma unroll
    for (int ktp = 0; ktp < 2; ktp++) {
      PU paf[4];
#pragma unroll
      for (int kth = 0; kth < 2; kth++) {
        int kt = ktp * 2 + kth;
        short8 k0 = *(const short8*)&Kg[((kt * 2 + 0) * 64 + lane) * 8];
        short8 k1 = *(const short8*)&Kg[((kt * 2 + 1) * 64 + lane) * 8];
#pragma unroll
        for (int mt = 0; mt < 4; mt++) {
          f32x4 st = mlc[kt];             // mask*log2e as accumulator init
          st = MFMA32(k0, qf[mt][0], st);
          st = MFMA32(k1, qf[mt][1], st);
          paf[mt].h2[kth] = pack4(EXP2(st[0]), EXP2(st[1]), EXP2(st[2]), EXP2(st[3]));
        }
      }
      // l rowsum on full-rate mfma32 (K=32 across the permuted slots)
#pragma unroll
      for (int mt = 0; mt < 4; mt++)
        la[mt] = MFMA32(paf[mt].v8, ones8, la[mt]);
      // PV: chunked blob read -> lane-contiguous 1KB per (ktp,nt), zero bank conflicts
#pragma unroll
      for (int nt = 0; nt < 4; nt++) {
        short8 vv = *(const short8*)&Vg[ktp * 2048 + (nt * 64 + lane) * 8];
#pragma unroll
        for (int mt = 0; mt < 4; mt++)
          of[mt][nt] = MFMA32(paf[mt].v8, vv, of[mt][nt]);
      }
    }
    __builtin_amdgcn_s_setprio(0);
#pragma unroll
    for (int kt = 0; kt < 4; kt++) mlc[kt] = mln[kt];
  }

  // merge group partials (additive). la is in C-layout: row q=quad*4+r, cols equal.
  __syncthreads();
  if (grp == 1) {
#pragma unroll
    for (int mt = 0; mt < 4; mt++) {
#pragma unroll
      for (int nt = 0; nt < 4; nt++)
#pragma unroll
        for (int r = 0; r < 4; r++)
          Ox[(wg * 64 + mt * 16 + quad * 4 + r) * 64 + nt * 16 + l15] = of[mt][nt][r];
      if (l15 == 0)
#pragma unroll
        for (int r = 0; r < 4; r++) Ll[wg * 64 + mt * 16 + quad * 4 + r] = la[mt][r];
    }
  }
  __syncthreads();
  if (grp == 0) {
#pragma unroll
    for (int mt = 0; mt < 4; mt++)
#pragma unroll
      for (int r = 0; r < 4; r++) {
        int ql = wg * 64 + mt * 16 + quad * 4 + r;
        float inv = 1.0f / (la[mt][r] + Ll[ql]);
        int q = qb * 128 + ql;
#pragma unroll
        for (int nt = 0; nt < 4; nt++) {
          float ov = of[mt][nt][r] + Ox[ql * 64 + nt * 16 + l15];
          ctx[(size_t)(b * SQL + q) * DM + h * DK + nt * 16 + l15] = f2bf(ov * inv);
        }
      }
  }
}

// ---------------- O projection + residual (round-0 measured-best loop, 128x128) ----------------
__global__ void ogemm_kernel(const u16* __restrict__ A, const u16* __restrict__ Bt,
                             float* __restrict__ C, const float* __restrict__ resid) {
  const int K = 1024;
  __shared__ __align__(16) u16 Al[128 * 32];
  __shared__ __align__(16) u16 Bl[128 * 32];
  int tid = threadIdx.x, lane = tid & 63, w = tid >> 6;
  int l15 = lane & 15, quad = lane >> 4;
  int wy = w >> 1, wx = w & 1;
  int tm = blockIdx.x * 128, tn = blockIdx.y * 128;
  f32x4 acc[4][4] = {};

  for (int k0 = 0; k0 < K; k0 += 32) {
    __syncthreads();
#pragma unroll
    for (int r = 0; r < 2; r++) {
      int mg = w * 2 + r;
      gload16(A + (size_t)(tm + mg * 16 + l15) * K + k0 + quad * 8, &Al[mg * 512]);
      gload16(Bt + (size_t)(tn + mg * 16 + l15) * K + k0 + quad * 8, &Bl[mg * 512]);
    }
    __syncthreads();
    short8 af[4], bfr[4];
#pragma unroll
    for (int i = 0; i < 4; i++) {
      af[i] = *(const short8*)&Al[((wy * 4 + i) * 64 + lane) * 8];
      bfr[i] = *(const short8*)&Bl[((wx * 4 + i) * 64 + lane) * 8];
    }
#pragma unroll
    for (int mt = 0; mt < 4; mt++)
#pragma unroll
      for (int nt = 0; nt < 4; nt++)
        acc[mt][nt] = MFMA32(af[mt], bfr[nt], acc[mt][nt]);
  }

#pragma unroll
  for (int mt = 0; mt < 4; mt++) {
    int m0 = tm + wy * 64 + mt * 16 + quad * 4;
#pragma unroll
    for (int nt = 0; nt < 4; nt++) {
      int n = tn + wx * 64 + nt * 16 + l15;
#pragma unroll
      for (int r = 0; r < 4; r++) {
        size_t idx = (size_t)(m0 + r) * 1024 + n;
        C[idx] = resid[idx] + acc[mt][nt][r];
      }
    }
  }
}

extern "C" void kernel_launch(void* const* d_in, const int* in_sizes, int n_in,
                              void* d_out, int out_size, void* d_ws, size_t ws_size,
                              hipStream_t stream) {
  const float* hidden = (const float*)d_in[0];
  const float* kvs    = (const float*)d_in[1];
  const float* mask   = (const float*)d_in[2];
  const float* lnw    = (const float*)d_in[3];
  const float* Wq     = (const float*)d_in[4];
  const float* Wk     = (const float*)d_in[5];
  const float* Wv     = (const float*)d_in[6];
  const float* Wo     = (const float*)d_in[7];
  char* ws = (char*)d_ws;

  u16* normed = (u16*)(ws + 0);           // 8 MB
  u16* kvb    = (u16*)(ws + 8388608);     // 16 MB
  u16* Wqt    = (u16*)(ws + 25165824);    // 2 MB
  u16* Wkt    = (u16*)(ws + 27262976);    // 2 MB
  u16* Wvt    = (u16*)(ws + 29360128);    // 2 MB
  u16* Wot    = (u16*)(ws + 31457280);    // 2 MB
  u16* Qb     = (u16*)(ws + 33554432);    // 8 MB (pre-scaled by log2e)
  u16* Kbf    = (u16*)(ws + 41943040);    // 16 MB
  u16* Vtb    = (u16*)(ws + 58720256);    // 16 MB (chunked mfma32 blob layout)
  u16* ctxb   = (u16*)(ws + 75497472);    // 8 MB

  pre_kernel<<<16384, 256, 0, stream>>>(hidden, lnw, kvs, Wq, Wk, Wv, Wo,
                                        normed, kvb, Wqt, Wkt, Wvt, Wot);
  proj_kernel<<<512, 512, 0, stream>>>(normed, kvb, Wqt, Wkt, Wvt, Qb, Kbf, Vtb);
  flash_kernel<<<dim3(SQL / 128, BB * NH), 256, 0, stream>>>(Qb, Kbf, Vtb, mask, ctxb);
  ogemm_kernel<<<dim3(32, 8), 256, 0, stream>>>(ctxb, Wot, (float*)d_out, hidden);
}